// Round 3
// baseline (126.977 us; speedup 1.0000x reference)
//
#include <hip/hip_runtime.h>
#include <hip/hip_bf16.h>

// Problem constants (B=2, S=2048, E=1024, H=16, Dh=64)
#define S_LEN 2048
#define EMB   1024
#define NH    16
#define DH    64
#define QKV_LD 3072   // 3*EMB

typedef __attribute__((ext_vector_type(8)))  __bf16 bf16x8;
typedef __attribute__((ext_vector_type(4)))  __bf16 bf16x4;
typedef __attribute__((ext_vector_type(4)))  float  f32x4;
typedef __attribute__((ext_vector_type(16))) float  f32x16;
typedef __attribute__((ext_vector_type(2)))  unsigned int u32x2;

// ---- async global->LDS (16B per lane; LDS dst = wave-uniform base) ----
__device__ __forceinline__ void gl_lds16(const void* g, void* l) {
  __builtin_amdgcn_global_load_lds(
      (const __attribute__((address_space(1))) void*)g,
      (__attribute__((address_space(3))) void*)l,
      16, 0, 0);
}

// ---------------- fused prep: cast x -> bf16, transpose+cast both weights --
__global__ __launch_bounds__(256)
void prep_fused(const float* __restrict__ x, __bf16* __restrict__ xb,
                const float* __restrict__ w_attn, __bf16* __restrict__ wat,
                const float* __restrict__ w_proj, __bf16* __restrict__ wpt,
                int n8) {
  __shared__ float T[64][65];
  const int bid = blockIdx.x;
  const int tid = threadIdx.x;

  if (bid < 2048) {
    int i = bid * 256 + tid;
    if (i >= n8) return;
    const f32x4* p = (const f32x4*)(x + (size_t)i * 8);
    f32x4 a = p[0], b = p[1];
    bf16x8 o;
    #pragma unroll
    for (int j = 0; j < 4; j++) { o[j] = (__bf16)a[j]; o[4 + j] = (__bf16)b[j]; }
    *(bf16x8*)(xb + (size_t)i * 8) = o;
    return;
  }

  const float* W; __bf16* Wt; int K, N, k0, n0;
  if (bid < 2048 + 768) {
    int t = bid - 2048;                 // w_attn: N=3072 -> 48 x-tiles, 16 k-tiles
    W = w_attn; Wt = wat; K = 1024; N = 3072;
    n0 = (t % 48) * 64; k0 = (t / 48) * 64;
  } else {
    int t = bid - 2816;                 // w_proj: 16 x 16 tiles
    W = w_proj; Wt = wpt; K = 1024; N = 1024;
    n0 = (t & 15) * 64; k0 = (t >> 4) * 64;
  }
  #pragma unroll
  for (int t = 0; t < 16; t++) {
    int idx = tid + t * 256;
    int r = idx >> 6, c = idx & 63;
    T[r][c] = W[(size_t)(k0 + r) * N + n0 + c];
  }
  __syncthreads();
  #pragma unroll
  for (int t = 0; t < 16; t++) {
    int idx = tid + t * 256;
    int r = idx >> 6, c = idx & 63;     // r = local n, c = local k
    Wt[(size_t)(n0 + r) * K + k0 + c] = (__bf16)T[c][r];
  }
}

// ---------------- bf16 MFMA GEMM: C(MxN) = A(MxK) @ Bt(NxK)^T -------------
#define TM 128
#define TK 32

template <typename OutT, int TNv>
__global__ __launch_bounds__(256, 2)
void gemm_bf16_mfma(const __bf16* __restrict__ A, const __bf16* __restrict__ Bt,
                    OutT* __restrict__ C, int M, int N, int K) {
  __shared__ __align__(16) __bf16 As[2][TM][TK];
  __shared__ __align__(16) __bf16 Bs[2][TNv][TK];
  const int tid  = threadIdx.x;
  const int lane = tid & 63;
  const int w    = tid >> 6;
  const int wr   = w >> 1, wc = w & 1;
  const int brow = blockIdx.y * TM;
  const int bcol = blockIdx.x * TNv;
  const int l15  = lane & 15;
  const int grp  = lane >> 4;

  constexpr int NBI = TNv / 64;        // B staging issues per wave
  constexpr int WCT = TNv / 2;         // wave column tile
  constexpr int NN  = WCT / 16;        // n-fragments per wave

  auto stage = [&](int k0, int buf) {
    #pragma unroll
    for (int j = 0; j < 2; j++) {       // A: 128x32 = 512 chunks, 2/wave
      const int cid = w * 128 + j * 64 + lane;
      const int row = cid >> 2, k8 = (cid & 3) * 8;
      gl_lds16(A + (size_t)(brow + row) * K + k0 + k8,
               &As[buf][0][0] + (size_t)(w * 128 + j * 64) * 8);
    }
    #pragma unroll
    for (int j = 0; j < NBI; j++) {     // B: TNv x 32 chunks
      const int cid = (w * NBI + j) * 64 + lane;
      const int row = cid >> 2, k8 = (cid & 3) * 8;
      gl_lds16(Bt + (size_t)(bcol + row) * K + k0 + k8,
               &Bs[buf][0][0] + (size_t)((w * NBI + j) * 64) * 8);
    }
  };

  f32x4 acc[4][NN];
  #pragma unroll
  for (int m = 0; m < 4; m++)
    #pragma unroll
    for (int n = 0; n < NN; n++) acc[m][n] = (f32x4){0.f, 0.f, 0.f, 0.f};

  stage(0, 0);
  __syncthreads();                      // drains prologue vmcnt

  const int nk = K / TK;
  for (int kt = 0; kt < nk; kt++) {
    const int cur = kt & 1;
    if (kt + 1 < nk) stage((kt + 1) * TK, cur ^ 1);   // prefetch under MFMA

    bf16x8 a[4], b[NN];
    #pragma unroll
    for (int m = 0; m < 4; m++)
      a[m] = *(const bf16x8*)&As[cur][wr * 64 + m * 16 + l15][grp * 8];
    #pragma unroll
    for (int n = 0; n < NN; n++)
      b[n] = *(const bf16x8*)&Bs[cur][wc * WCT + n * 16 + l15][grp * 8];
    #pragma unroll
    for (int m = 0; m < 4; m++)
      #pragma unroll
      for (int n = 0; n < NN; n++)
        acc[m][n] = __builtin_amdgcn_mfma_f32_16x16x32_bf16(a[m], b[n], acc[m][n], 0, 0, 0);

    __syncthreads();   // all waves done reading cur; prefetch landed
  }

  #pragma unroll
  for (int m = 0; m < 4; m++)
    #pragma unroll
    for (int r = 0; r < 4; r++) {
      const size_t row = (size_t)(brow + wr * 64 + m * 16 + grp * 4 + r);
      #pragma unroll
      for (int n = 0; n < NN; n++)
        C[row * N + bcol + wc * WCT + n * 16 + l15] = (OutT)acc[m][n][r];
    }
}

// ---------------- MFMA flash attention v16: counted-vmcnt pipeline --------
// v15 post-mortem: per-chain iteration time ~3000 cyc regardless of chain
// length; only ~800 cyc is busy work.  The per-iteration __syncthreads()
// (vmcnt(0) lgkmcnt(0) drain) serializes load latency + barrier skew into
// every iteration.  v16: 3 LDS buffers, prologue stages 2 tiles, each
// iteration waits vmcnt(4) (tile t done, t+1 in flight -- NEVER 0 in the
// main loop), raw s_barrier, stages t+2 into buf (t+2)%3.
// Safety: stage(t+2) overwrites buf (t-1)%3; all waves finished reading
// tile t-1 before barrier t (barrier instances are matched in order), and
// each wave's own vmcnt(4) before barrier t guarantees ITS tile-t chunks
// landed, so after the barrier all of tile t is visible to all waves.
// Also: dual-accumulator QK^T (halves MFMA dep chain), tree max/psum
// reductions (depth 4 vs 15), tr_reads issued right after QK^T.
// Split-K schedule (qtiles 20..31 split, cached partials) kept from v15.
#define QB 64
#define KB 64
#define QSCALE 0.18033688f   // 0.125 * log2(e)

// item code = qtile*4 + khalf*2 + split, sorted by length descending (LPT)
__device__ __constant__ unsigned char ITEMS[44] = {
  76, 72, 68, 64,                 // unsplit q19..q16 (len 20..17)
  125, 127, 121, 60,              // 31h0,31h1,30h0 (16), u15 (16)
  123, 117, 119, 113, 56,         // 30h1,29h0,29h1,28h0 (15), u14
  115, 109, 111, 105, 52,         // 28h1,27h0,27h1,26h0 (14), u13
  107, 101, 103, 97, 48,          // 26h1,25h0,25h1,24h0 (13), u12
  99, 93, 95, 89, 44,             // 24h1,23h0,23h1,22h0 (12), u11
  91, 85, 87, 81, 40,             // 22h1,21h0,21h1,20h0 (11), u10
  83, 36,                         // 20h1 (10), u9
  32, 28, 24, 20, 16, 12, 8, 4, 0 // u8..u0
};

__global__ __launch_bounds__(256, 4)
void attn_mfma(const __bf16* __restrict__ qkv, __bf16* __restrict__ y,
               float* __restrict__ pO, float* __restrict__ pml) {
  __shared__ __align__(16) __bf16 Ks[3][KB][64];   // 24 KB
  __shared__ __align__(16) __bf16 Vs[3][4096];     // 24 KB

  const int tid  = threadIdx.x;
  const int lane = tid & 63;
  const int w    = tid >> 6;

  // ---- work-item decode: 1408 blocks = 8 XCD x 4 groups x 44 items ----
  const int bid = blockIdx.x;                 // 0..1407
  const int xcd = bid & 7;
  const int j   = bid >> 3;                   // 0..175
  const int g   = xcd * 4 + j / 44;           // (b,h) group 0..31
  const int idx = j % 44;

  const int code  = ITEMS[idx];
  const bool split = code & 1;
  const int khalf = (code >> 1) & 1;
  const int qtile = code >> 2;

  int it0, it1;
  bool diag;
  if (!split) {
    it0 = 0; it1 = qtile + 1; diag = true;
  } else {
    const int half = (qtile + 2) >> 1;        // ceil((qtile+1)/2)
    it0 = khalf ? half : 0;
    it1 = khalf ? qtile + 1 : half;
    diag = (khalf == 1);
  }
  const int h = g & 15, b = g >> 4;
  const int pidx = split ? ((g * 12 + (qtile - 20)) * 2 + khalf) : 0;

  const __bf16* base = qkv + (size_t)b * S_LEN * QKV_LD;

  const int l31 = lane & 31;
  const int hl  = lane >> 5;          // lane half (0/1)
  const int qh  = w >> 1;             // q-half of the 64-row tile
  const int kh  = w & 1;              // k-half of each 64-key tile

  // tr_read per-lane base: column (lane&15) of the [4][16] subtile; the
  // db/sk selection comes from the address (law verified against v10).
  const int voff32 = ((lane >> 4) & 1) * 2048 + hl * 128 + (lane & 15) * 8
                   + kh * 1024;

  auto stageK = [&](int j0, int buf) {
    #pragma unroll
    for (int jj = 0; jj < 2; jj++) {
      const int cid = w * 128 + jj * 64 + lane;    // chunk 0..511
      const int r = cid >> 3, pc = cid & 7;
      const int lc = pc ^ (r & 7);                 // inverse swizzle on source
      gl_lds16(base + (size_t)(j0 + r) * QKV_LD + EMB + h * DH + lc * 8,
               (char*)&Ks[buf][0][0] + (w * 128 + jj * 64) * 16);
    }
  };
  auto stageV = [&](int j0, int buf) {
    #pragma unroll
    for (int jj = 0; jj < 2; jj++) {
      const int cid = w * 128 + jj * 64 + lane;
      const int db = cid >> 7, sk = (cid >> 3) & 15;
      const int jr = (cid >> 1) & 3, ch = cid & 1;
      gl_lds16(base + (size_t)(j0 + sk * 4 + jr) * QKV_LD + 2 * EMB + h * DH
                    + db * 16 + ch * 8,
               (char*)&Vs[buf][0] + (w * 128 + jj * 64) * 16);
    }
  };

  const int qbase = qtile * QB;
  const int q = qbase + qh * 32 + l31;           // this lane's q row

  // Q B-fragments (col=q, k_hw=d): qf[dq][i] = Q[q][dq*16 + hl*8 + i]
  bf16x8 qf[4];
  {
    const __bf16* qp = base + (size_t)q * QKV_LD + h * DH;
    #pragma unroll
    for (int dq = 0; dq < 4; dq++) {
      bf16x8 v = *(const bf16x8*)(qp + dq * 16 + hl * 8);
      #pragma unroll
      for (int i2 = 0; i2 < 8; i2++) qf[dq][i2] = (__bf16)((float)v[i2] * QSCALE);
    }
  }

  f32x16 o_acc[2];
  #pragma unroll
  for (int d2 = 0; d2 < 2; d2++)
    #pragma unroll
    for (int r = 0; r < 16; r++) o_acc[d2][r] = 0.f;
  float m = -1e30f, l = 0.f;

  // Process one K-tile: QK^T -> (masked?) online softmax -> PV.
  auto process = [&](int cur, int j0, bool masked) {
    // ---- S^T = K Q (32k x 32q), dual accumulator halves the dep chain ----
    // s[reg]: k = j0 + kh*32 + (reg&3) + 8*(reg>>2) + 4*hl, q = l31.
    f32x16 s, s2;
    #pragma unroll
    for (int r = 0; r < 16; r++) { s[r] = 0.f; s2[r] = 0.f; }
    const int krow = kh * 32 + l31;
    bf16x8 kf0 = *(const bf16x8*)&Ks[cur][krow][((0 + hl) ^ (krow & 7)) * 8];
    bf16x8 kf1 = *(const bf16x8*)&Ks[cur][krow][((2 + hl) ^ (krow & 7)) * 8];
    bf16x8 kf2 = *(const bf16x8*)&Ks[cur][krow][((4 + hl) ^ (krow & 7)) * 8];
    bf16x8 kf3 = *(const bf16x8*)&Ks[cur][krow][((6 + hl) ^ (krow & 7)) * 8];
    __builtin_amdgcn_s_setprio(1);
    s  = __builtin_amdgcn_mfma_f32_32x32x16_bf16(kf0, qf[0], s,  0, 0, 0);
    s2 = __builtin_amdgcn_mfma_f32_32x32x16_bf16(kf1, qf[1], s2, 0, 0, 0);
    s  = __builtin_amdgcn_mfma_f32_32x32x16_bf16(kf2, qf[2], s,  0, 0, 0);
    s2 = __builtin_amdgcn_mfma_f32_32x32x16_bf16(kf3, qf[3], s2, 0, 0, 0);
    __builtin_amdgcn_s_setprio(0);

    // ---- issue all 8 V^T transpose reads early; latency hides under SM ----
    const unsigned vb =
        (unsigned)(uintptr_t)(__attribute__((address_space(3))) char*)(&Vs[cur][0])
        + (unsigned)voff32;
    u32x2 tv[8];
    asm volatile("ds_read_b64_tr_b16 %0, %1 offset:0"    : "=v"(tv[0]) : "v"(vb));
    asm volatile("ds_read_b64_tr_b16 %0, %1 offset:256"  : "=v"(tv[1]) : "v"(vb));
    asm volatile("ds_read_b64_tr_b16 %0, %1 offset:512"  : "=v"(tv[2]) : "v"(vb));
    asm volatile("ds_read_b64_tr_b16 %0, %1 offset:768"  : "=v"(tv[3]) : "v"(vb));
    asm volatile("ds_read_b64_tr_b16 %0, %1 offset:4096" : "=v"(tv[4]) : "v"(vb));
    asm volatile("ds_read_b64_tr_b16 %0, %1 offset:4352" : "=v"(tv[5]) : "v"(vb));
    asm volatile("ds_read_b64_tr_b16 %0, %1 offset:4608" : "=v"(tv[6]) : "v"(vb));
    asm volatile("ds_read_b64_tr_b16 %0, %1 offset:4864" : "=v"(tv[7]) : "v"(vb));

    #pragma unroll
    for (int r = 0; r < 16; r++) s[r] += s2[r];

    if (masked) {
      const int lim = q - j0 - kh * 32 - 4 * hl;   // keep if (reg&3)+8*(reg>>2) <= lim
      #pragma unroll
      for (int r = 0; r < 16; r++) {
        const int kl = (r & 3) + 8 * (r >> 2);
        if (kl > lim) s[r] = -2e30f;    // -2e30: exp2(s-m)==0 even when m=-1e30
      }
    }

    // ---- max reduce: depth-4 tree + ONE cross-half shuffle ----
    float x0 = fmaxf(s[0], s[8]),  x1 = fmaxf(s[1], s[9]);
    float x2 = fmaxf(s[2], s[10]), x3 = fmaxf(s[3], s[11]);
    float x4 = fmaxf(s[4], s[12]), x5 = fmaxf(s[5], s[13]);
    float x6 = fmaxf(s[6], s[14]), x7 = fmaxf(s[7], s[15]);
    x0 = fmaxf(x0, x4); x1 = fmaxf(x1, x5);
    x2 = fmaxf(x2, x6); x3 = fmaxf(x3, x7);
    x0 = fmaxf(x0, x2); x1 = fmaxf(x1, x3);
    float tmax = fmaxf(x0, x1);
    tmax = fmaxf(tmax, __shfl_xor(tmax, 32));

    const bool grow = !__all(tmax <= m + 8.0f);
    float corr = 1.f;
    if (grow) {
      const float mnew = fmaxf(m, tmax);
      corr = __builtin_amdgcn_exp2f(m - mnew);
      m = mnew;
    }

    // ---- exp2 + tree psum (VALU; covers the tr_read latency) ----
    float ps0 = 0.f, ps1 = 0.f, ps2 = 0.f, ps3 = 0.f;
    #pragma unroll
    for (int r = 0; r < 16; r += 4) {
      float p0 = __builtin_amdgcn_exp2f(s[r]     - m);
      float p1 = __builtin_amdgcn_exp2f(s[r + 1] - m);
      float p2 = __builtin_amdgcn_exp2f(s[r + 2] - m);
      float p3 = __builtin_amdgcn_exp2f(s[r + 3] - m);
      s[r] = p0; s[r + 1] = p1; s[r + 2] = p2; s[r + 3] = p3;
      ps0 += p0; ps1 += p1; ps2 += p2; ps3 += p3;
    }
    float psum = (ps0 + ps1) + (ps2 + ps3);

    // ---- P^T B-frags: fully in-lane (shared sigma with the A-side) ----
    bf16x8 pb0, pb1;
    #pragma unroll
    for (int i2 = 0; i2 < 8; i2++) {
      pb0[i2] = (__bf16)s[i2];
      pb1[i2] = (__bf16)s[8 + i2];
    }

    // ---- O-rescale must precede PV; l-update deferred past PV ----
    if (grow) {
      #pragma unroll
      for (int d2 = 0; d2 < 2; d2++)
        #pragma unroll
        for (int r = 0; r < 16; r++) o_acc[d2][r] *= corr;
    }

    // ---- single drain, then 4 back-to-back PV MFMAs ----
    asm volatile("s_waitcnt lgkmcnt(0)");
    __builtin_amdgcn_sched_barrier(0);
    __builtin_amdgcn_s_setprio(1);
    #pragma unroll
    for (int d2 = 0; d2 < 2; d2++) {
      bf16x8 a0, a1;
      ((u32x2*)&a0)[0] = tv[d2 * 4 + 0]; ((u32x2*)&a0)[1] = tv[d2 * 4 + 1];
      ((u32x2*)&a1)[0] = tv[d2 * 4 + 2]; ((u32x2*)&a1)[1] = tv[d2 * 4 + 3];
      o_acc[d2] = __builtin_amdgcn_mfma_f32_32x32x16_bf16(a0, pb0, o_acc[d2], 0, 0, 0);
      o_acc[d2] = __builtin_amdgcn_mfma_f32_32x32x16_bf16(a1, pb1, o_acc[d2], 0, 0, 0);
    }
    __builtin_amdgcn_s_setprio(0);

    // ---- l-update (off the PV critical path) ----
    psum += __shfl_xor(psum, 32);
    l = grow ? (l * corr + psum) : (l + psum);
  };

  // ---- pipelined main loop: 3 buffers, counted vmcnt, raw barriers ----
  const int nt = it1 - it0;
  stageK(it0 * KB, 0);
  stageV(it0 * KB, 0);
  if (nt > 1) { stageK((it0 + 1) * KB, 1); stageV((it0 + 1) * KB, 1); }

  int cur = 0;
  #pragma unroll 1
  for (int tt = 0; tt < nt; tt++) {
    // tile tt's 4 loads done; tile tt+1's may stay in flight (never drain 0)
    if (tt < nt - 1) asm volatile("s_waitcnt vmcnt(4)" ::: "memory");
    else             asm volatile("s_waitcnt vmcnt(0)" ::: "memory");
    __builtin_amdgcn_s_barrier();
    __builtin_amdgcn_sched_barrier(0);
    if (tt + 2 < nt) {
      int nb = cur + 2; if (nb >= 3) nb -= 3;
      stageK((it0 + tt + 2) * KB, nb);
      stageV((it0 + tt + 2) * KB, nb);
    }
    process(cur, (it0 + tt) * KB, (tt == nt - 1) && diag);
    cur = (cur == 2) ? 0 : cur + 1;
  }

  // ---- kh-pair merge through LDS, then epilogue by kh=0 waves ----
  __syncthreads();     // full drain; reuse Ks/Vs as exchange space
  float* exO  = (float*)&Vs[0][0];      // [32 rows][128 slots] f32 = 16 KB
  float* exML = (float*)&Ks[0][0][0];   // [2][128] f32
  const int slot = qh * 64 + lane;
  if (kh) {
    #pragma unroll
    for (int r = 0; r < 16; r++) {
      exO[r * 128 + slot]        = o_acc[0][r];
      exO[(16 + r) * 128 + slot] = o_acc[1][r];
    }
    exML[slot]       = m;
    exML[128 + slot] = l;
  }
  __syncthreads();
  if (!kh) {
    const float m1  = exML[slot];
    const float l1v = exML[128 + slot];
    const float mm = fmaxf(m, m1);
    const float c0 = __builtin_amdgcn_exp2f(m - mm);
    const float c1 = __builtin_amdgcn_exp2f(m1 - mm);
    const float lsum = l * c0 + l1v * c1;
    if (split) {
      // unnormalized f32 partial + (m,l) for attn_merge (cached workspace)
      float* prow = pO + (size_t)pidx * 4096 + (size_t)(qh * 32 + l31) * 64;
      #pragma unroll
      for (int d2 = 0; d2 < 2; d2++)
        #pragma unroll
        for (int rq = 0; rq < 4; rq++) {
          f32x4 o4;
          #pragma unroll
          for (int jj = 0; jj < 4; jj++) {
            const int r = rq * 4 + jj;
            o4[jj] = o_acc[d2][r] * c0 + exO[(d2 * 16 + r) * 128 + slot] * c1;
          }
          *(f32x4*)&prow[d2 * 32 + rq * 8 + hl * 4] = o4;
        }
      if (!hl) {
        pml[(size_t)pidx * 128 + qh * 32 + l31]      = mm;
        pml[(size_t)pidx * 128 + 64 + qh * 32 + l31] = lsum;
      }
    } else {
      const float inv = 1.f / lsum;
      __bf16* yrow = y + ((size_t)(b * S_LEN + q)) * EMB + h * DH;
      #pragma unroll
      for (int d2 = 0; d2 < 2; d2++)
        #pragma unroll
        for (int rq = 0; rq < 4; rq++) {
          bf16x4 o4;
          #pragma unroll
          for (int jj = 0; jj < 4; jj++) {
            const int r = rq * 4 + jj;
            float v = (o_acc[d2][r] * c0 + exO[(d2 * 16 + r) * 128 + slot] * c1) * inv;
            o4[jj] = (__bf16)v;
          }
          // d = d2*32 + rq*8 + hl*4 + jj
          *(bf16x4*)&yrow[d2 * 32 + rq * 8 + hl * 4] = o4;
        }
    }
  }
}

// ---------------- merge the two K-half partials of qtiles 20..31 ----------
__global__ __launch_bounds__(256)
void attn_merge(const float* __restrict__ pO, const float* __restrict__ pml,
                __bf16* __restrict__ y) {
  const int mid = blockIdx.x;            // 0..383
  const int g = mid / 12, qrel = mid % 12;
  const int qt = 20 + qrel;
  const int b = g >> 4, h = g & 15;
  const int p0 = (g * 12 + qrel) * 2, p1 = p0 + 1;
  const int row = threadIdx.x >> 2;            // 0..63
  const int d0  = (threadIdx.x & 3) * 16;      // 0,16,32,48

  const float mA = pml[(size_t)p0 * 128 + row];
  const float lA = pml[(size_t)p0 * 128 + 64 + row];
  const float mB = pml[(size_t)p1 * 128 + row];
  const float lB = pml[(size_t)p1 * 128 + 64 + row];
  const float mm = fmaxf(mA, mB);
  const float cA = __builtin_amdgcn_exp2f(mA - mm);
  const float cB = __builtin_amdgcn_exp2f(mB - mm);
  const float inv = 1.f / (lA * cA + lB * cB);

  const float* OA = pO + (size_t)p0 * 4096 + (size_t)row * 64 + d0;
  const float* OB = pO + (size_t)p1 * 4096 + (size_t)row * 64 + d0;
  __bf16* yr = y + ((size_t)(b * S_LEN + qt * 64 + row)) * EMB + h * DH + d0;
  #pragma unroll
  for (int i = 0; i < 4; i++) {
    f32x4 va = *(const f32x4*)(OA + i * 4);
    f32x4 vb = *(const f32x4*)(OB + i * 4);
    bf16x4 o;
    #pragma unroll
    for (int jj = 0; jj < 4; jj++)
      o[jj] = (__bf16)((va[jj] * cA + vb[jj] * cB) * inv);
    *(bf16x4*)(yr + i * 4) = o;
  }
}

// ---------------- Launch ----------------
extern "C" void kernel_launch(void* const* d_in, const int* in_sizes, int n_in,
                              void* d_out, int out_size, void* d_ws, size_t ws_size,
                              hipStream_t stream) {
  const float* x      = (const float*)d_in[0];  // (B, S, E)
  const float* w_attn = (const float*)d_in[1];  // (E, 3E)
  const float* w_proj = (const float*)d_in[2];  // (E, E)
  float* out = (float*)d_out;                   // (B, S, E)

  const int B = in_sizes[0] / (S_LEN * EMB);    // = 2
  const int M = B * S_LEN;                      // 4096

  // bf16 workspace layout
  __bf16* xb   = (__bf16*)d_ws;                       // M x E          (8 MB)
  __bf16* wat  = xb  + (size_t)M * EMB;               // 3E x E transp  (6 MB)
  __bf16* wpt  = wat + (size_t)QKV_LD * EMB;          // E x E transp   (2 MB)
  __bf16* qkvb = wpt + (size_t)EMB * EMB;             // M x 3E         (24 MB)
  __bf16* yb   = qkvb + (size_t)M * QKV_LD;           // M x E          (8 MB)

  // split-K partials live in CACHED ws: xb+wat (14 MB contiguous, dead after
  // gemm1).  pO = 768 x 4096 f32 = 12 MB; pml = 768 x 128 f32 = 384 KB.
  float* pO  = (float*)d_ws;
  float* pml = pO + (size_t)768 * 4096;

  // 0) fused prep: cast + both weight transposes in one launch
  {
    int n8 = (M * EMB) / 8;   // 524288 -> 2048 cast blocks
    prep_fused<<<dim3(3072), 256, 0, stream>>>(x, xb, w_attn, wat, w_proj, wpt, n8);
  }

  // 1) qkv = x @ w_attn  (bf16 out, TN=128: grid 768 = 3 blocks/CU)
  dim3 g1(QKV_LD / 128, M / TM);
  gemm_bf16_mfma<__bf16, 128><<<g1, 256, 0, stream>>>(xb, wat, qkvb, M, QKV_LD, EMB);

  // 2) y = causal_attention(qkv)  [v16: 3-buffer counted-vmcnt pipeline]
  attn_mfma<<<dim3(1408), 256, 0, stream>>>(qkvb, yb, pO, pml);
  attn_merge<<<dim3(384), 256, 0, stream>>>(pO, pml, yb);

  // 3) out = y @ w_proj  (f32 out, TN=64: grid 512 = 2 blocks/CU)
  dim3 g3(EMB / 64, M / TM);
  gemm_bf16_mfma<float, 64><<<g3, 256, 0, stream>>>(yb, wpt, out, M, EMB, EMB);
}

// Round 4
// 109.630 us; speedup vs baseline: 1.1582x; 1.1582x over previous
//
#include <hip/hip_runtime.h>
#include <hip/hip_bf16.h>

// Problem constants (B=2, S=2048, E=1024, H=16, Dh=64)
#define S_LEN 2048
#define EMB   1024
#define NH    16
#define DH    64
#define QKV_LD 3072   // 3*EMB

typedef __attribute__((ext_vector_type(8)))  __bf16 bf16x8;
typedef __attribute__((ext_vector_type(4)))  __bf16 bf16x4;
typedef __attribute__((ext_vector_type(4)))  float  f32x4;
typedef __attribute__((ext_vector_type(16))) float  f32x16;
typedef __attribute__((ext_vector_type(2)))  unsigned int u32x2;

// ---- async global->LDS (16B per lane; LDS dst = wave-uniform base) ----
__device__ __forceinline__ void gl_lds16(const void* g, void* l) {
  __builtin_amdgcn_global_load_lds(
      (const __attribute__((address_space(1))) void*)g,
      (__attribute__((address_space(3))) void*)l,
      16, 0, 0);
}

// ---------------- fused prep: cast x -> bf16, transpose+cast both weights --
__global__ __launch_bounds__(256)
void prep_fused(const float* __restrict__ x, __bf16* __restrict__ xb,
                const float* __restrict__ w_attn, __bf16* __restrict__ wat,
                const float* __restrict__ w_proj, __bf16* __restrict__ wpt,
                int n8) {
  __shared__ float T[64][65];
  const int bid = blockIdx.x;
  const int tid = threadIdx.x;

  if (bid < 2048) {
    int i = bid * 256 + tid;
    if (i >= n8) return;
    const f32x4* p = (const f32x4*)(x + (size_t)i * 8);
    f32x4 a = p[0], b = p[1];
    bf16x8 o;
    #pragma unroll
    for (int j = 0; j < 4; j++) { o[j] = (__bf16)a[j]; o[4 + j] = (__bf16)b[j]; }
    *(bf16x8*)(xb + (size_t)i * 8) = o;
    return;
  }

  const float* W; __bf16* Wt; int K, N, k0, n0;
  if (bid < 2048 + 768) {
    int t = bid - 2048;                 // w_attn: N=3072 -> 48 x-tiles, 16 k-tiles
    W = w_attn; Wt = wat; K = 1024; N = 3072;
    n0 = (t % 48) * 64; k0 = (t / 48) * 64;
  } else {
    int t = bid - 2816;                 // w_proj: 16 x 16 tiles
    W = w_proj; Wt = wpt; K = 1024; N = 1024;
    n0 = (t & 15) * 64; k0 = (t >> 4) * 64;
  }
  #pragma unroll
  for (int t = 0; t < 16; t++) {
    int idx = tid + t * 256;
    int r = idx >> 6, c = idx & 63;
    T[r][c] = W[(size_t)(k0 + r) * N + n0 + c];
  }
  __syncthreads();
  #pragma unroll
  for (int t = 0; t < 16; t++) {
    int idx = tid + t * 256;
    int r = idx >> 6, c = idx & 63;     // r = local n, c = local k
    Wt[(size_t)(n0 + r) * K + k0 + c] = (__bf16)T[c][r];
  }
}

// ---------------- bf16 MFMA GEMM: C(MxN) = A(MxK) @ Bt(NxK)^T -------------
#define TM 128
#define TK 32

template <typename OutT, int TNv>
__global__ __launch_bounds__(256, 2)
void gemm_bf16_mfma(const __bf16* __restrict__ A, const __bf16* __restrict__ Bt,
                    OutT* __restrict__ C, int M, int N, int K) {
  __shared__ __align__(16) __bf16 As[2][TM][TK];
  __shared__ __align__(16) __bf16 Bs[2][TNv][TK];
  const int tid  = threadIdx.x;
  const int lane = tid & 63;
  const int w    = tid >> 6;
  const int wr   = w >> 1, wc = w & 1;
  const int brow = blockIdx.y * TM;
  const int bcol = blockIdx.x * TNv;
  const int l15  = lane & 15;
  const int grp  = lane >> 4;

  constexpr int NBI = TNv / 64;        // B staging issues per wave
  constexpr int WCT = TNv / 2;         // wave column tile
  constexpr int NN  = WCT / 16;        // n-fragments per wave

  auto stage = [&](int k0, int buf) {
    #pragma unroll
    for (int j = 0; j < 2; j++) {       // A: 128x32 = 512 chunks, 2/wave
      const int cid = w * 128 + j * 64 + lane;
      const int row = cid >> 2, k8 = (cid & 3) * 8;
      gl_lds16(A + (size_t)(brow + row) * K + k0 + k8,
               &As[buf][0][0] + (size_t)(w * 128 + j * 64) * 8);
    }
    #pragma unroll
    for (int j = 0; j < NBI; j++) {     // B: TNv x 32 chunks
      const int cid = (w * NBI + j) * 64 + lane;
      const int row = cid >> 2, k8 = (cid & 3) * 8;
      gl_lds16(Bt + (size_t)(bcol + row) * K + k0 + k8,
               &Bs[buf][0][0] + (size_t)((w * NBI + j) * 64) * 8);
    }
  };

  f32x4 acc[4][NN];
  #pragma unroll
  for (int m = 0; m < 4; m++)
    #pragma unroll
    for (int n = 0; n < NN; n++) acc[m][n] = (f32x4){0.f, 0.f, 0.f, 0.f};

  stage(0, 0);
  __syncthreads();                      // drains prologue vmcnt

  const int nk = K / TK;
  for (int kt = 0; kt < nk; kt++) {
    const int cur = kt & 1;
    if (kt + 1 < nk) stage((kt + 1) * TK, cur ^ 1);   // prefetch under MFMA

    bf16x8 a[4], b[NN];
    #pragma unroll
    for (int m = 0; m < 4; m++)
      a[m] = *(const bf16x8*)&As[cur][wr * 64 + m * 16 + l15][grp * 8];
    #pragma unroll
    for (int n = 0; n < NN; n++)
      b[n] = *(const bf16x8*)&Bs[cur][wc * WCT + n * 16 + l15][grp * 8];
    #pragma unroll
    for (int m = 0; m < 4; m++)
      #pragma unroll
      for (int n = 0; n < NN; n++)
        acc[m][n] = __builtin_amdgcn_mfma_f32_16x16x32_bf16(a[m], b[n], acc[m][n], 0, 0, 0);

    __syncthreads();   // all waves done reading cur; prefetch landed
  }

  #pragma unroll
  for (int m = 0; m < 4; m++)
    #pragma unroll
    for (int r = 0; r < 4; r++) {
      const size_t row = (size_t)(brow + wr * 64 + m * 16 + grp * 4 + r);
      #pragma unroll
      for (int n = 0; n < NN; n++)
        C[row * N + bcol + wc * WCT + n * 16 + l15] = (OutT)acc[m][n][r];
    }
}

// ---------------- MFMA flash attention v17: 17 KB LDS, single-buffered ----
// v16 post-mortem: occupancy tracks max-LDS-blocks (32KB->occ25%, 48KB->
// occ16.5%) and duration tracks occupancy inversely; the per-iteration cost
// is latency that only co-resident chains can hide.  v17 shrinks LDS to
// 17 KB (K single 8KB + V single 8KB + 1KB exchange) so residency is
// register-capped (4 blocks/CU) instead of LDS-capped (~2).
// Single-buffering needs a 3-barrier schedule (windows ~300-600cy >> L2):
//   vmcnt(0); BARRIER X  (K,V of tile t landed on all waves)
//   QK; tr_issue; max-reduce
//   BARRIER Z  (all QK reads done -> Ks dead) ; stageK(t+1)
//   lgkmcnt(0); BARRIER Y (all tr reads done -> Vs dead) ; stageV(t+1)
//   exp/pack/rescale; PV
// Engine internals + split-K schedule (qtiles 20..31, cached partials)
// identical to v15 (42us version).
#define QB 64
#define KB 64
#define QSCALE 0.18033688f   // 0.125 * log2(e)

// item code = qtile*4 + khalf*2 + split, sorted by length descending (LPT)
__device__ __constant__ unsigned char ITEMS[44] = {
  76, 72, 68, 64,                 // unsplit q19..q16 (len 20..17)
  125, 127, 121, 60,              // 31h0,31h1,30h0 (16), u15 (16)
  123, 117, 119, 113, 56,         // 30h1,29h0,29h1,28h0 (15), u14
  115, 109, 111, 105, 52,         // 28h1,27h0,27h1,26h0 (14), u13
  107, 101, 103, 97, 48,          // 26h1,25h0,25h1,24h0 (13), u12
  99, 93, 95, 89, 44,             // 24h1,23h0,23h1,22h0 (12), u11
  91, 85, 87, 81, 40,             // 22h1,21h0,21h1,20h0 (11), u10
  83, 36,                         // 20h1 (10), u9
  32, 28, 24, 20, 16, 12, 8, 4, 0 // u8..u0
};

__global__ __launch_bounds__(256, 4)
void attn_mfma(const __bf16* __restrict__ qkv, __bf16* __restrict__ y,
               float* __restrict__ pO, float* __restrict__ pml) {
  // 17408 B total: Ks [64][64] bf16 (8KB) | Vs 4096 bf16 (8KB) | exML 1KB
  __shared__ __align__(16) char SMEM[17408];
  __bf16 (*Ks)[64] = (__bf16 (*)[64])SMEM;
  __bf16* Vs = (__bf16*)(SMEM + 8192);

  const int tid  = threadIdx.x;
  const int lane = tid & 63;
  const int w    = tid >> 6;

  // ---- work-item decode: 1408 blocks = 8 XCD x 4 groups x 44 items ----
  const int bid = blockIdx.x;                 // 0..1407
  const int xcd = bid & 7;
  const int j   = bid >> 3;                   // 0..175
  const int g   = xcd * 4 + j / 44;           // (b,h) group 0..31
  const int idx = j % 44;

  const int code  = ITEMS[idx];
  const bool split = code & 1;
  const int khalf = (code >> 1) & 1;
  const int qtile = code >> 2;

  int it0, it1;
  bool diag;
  if (!split) {
    it0 = 0; it1 = qtile + 1; diag = true;
  } else {
    const int half = (qtile + 2) >> 1;        // ceil((qtile+1)/2)
    it0 = khalf ? half : 0;
    it1 = khalf ? qtile + 1 : half;
    diag = (khalf == 1);
  }
  const int h = g & 15, b = g >> 4;
  const int pidx = split ? ((g * 12 + (qtile - 20)) * 2 + khalf) : 0;

  const __bf16* base = qkv + (size_t)b * S_LEN * QKV_LD;

  const int l31 = lane & 31;
  const int hl  = lane >> 5;          // lane half (0/1)
  const int qh  = w >> 1;             // q-half of the 64-row tile
  const int kh  = w & 1;              // k-half of each 64-key tile

  // tr_read per-lane base (single V buffer now)
  const int voff32 = ((lane >> 4) & 1) * 2048 + hl * 128 + (lane & 15) * 8
                   + kh * 1024;

  auto stageK = [&](int j0) {
    #pragma unroll
    for (int jj = 0; jj < 2; jj++) {
      const int cid = w * 128 + jj * 64 + lane;    // chunk 0..511
      const int r = cid >> 3, pc = cid & 7;
      const int lc = pc ^ (r & 7);                 // inverse swizzle on source
      gl_lds16(base + (size_t)(j0 + r) * QKV_LD + EMB + h * DH + lc * 8,
               SMEM + (w * 128 + jj * 64) * 16);
    }
  };
  auto stageV = [&](int j0) {
    #pragma unroll
    for (int jj = 0; jj < 2; jj++) {
      const int cid = w * 128 + jj * 64 + lane;
      const int db = cid >> 7, sk = (cid >> 3) & 15;
      const int jr = (cid >> 1) & 3, ch = cid & 1;
      gl_lds16(base + (size_t)(j0 + sk * 4 + jr) * QKV_LD + 2 * EMB + h * DH
                    + db * 16 + ch * 8,
               SMEM + 8192 + (w * 128 + jj * 64) * 16);
    }
  };

  const int qbase = qtile * QB;
  const int q = qbase + qh * 32 + l31;           // this lane's q row

  // Q B-fragments (col=q, k_hw=d): qf[dq][i] = Q[q][dq*16 + hl*8 + i]
  bf16x8 qf[4];
  {
    const __bf16* qp = base + (size_t)q * QKV_LD + h * DH;
    #pragma unroll
    for (int dq = 0; dq < 4; dq++) {
      bf16x8 v = *(const bf16x8*)(qp + dq * 16 + hl * 8);
      #pragma unroll
      for (int i2 = 0; i2 < 8; i2++) qf[dq][i2] = (__bf16)((float)v[i2] * QSCALE);
    }
  }

  f32x16 o_acc[2];
  #pragma unroll
  for (int d2 = 0; d2 < 2; d2++)
    #pragma unroll
    for (int r = 0; r < 16; r++) o_acc[d2][r] = 0.f;
  float m = -1e30f, l = 0.f;

  // One K-tile: X-barrier, QK^T, tr-issue, Z-barrier+stageK, Y-barrier+stageV,
  // softmax, PV.  jn = next tile's j0 (staged iff do_stage).
  auto iter = [&](int j0, bool masked, int jn, bool do_stage) {
    asm volatile("s_waitcnt vmcnt(0)" ::: "memory");
    __builtin_amdgcn_s_barrier();                      // X: K,V of tile t landed
    __builtin_amdgcn_sched_barrier(0);

    // ---- S^T = K Q (32k x 32q, chained over d) ----
    f32x16 s;
    #pragma unroll
    for (int r = 0; r < 16; r++) s[r] = 0.f;
    const int krow = kh * 32 + l31;
    __builtin_amdgcn_s_setprio(1);
    #pragma unroll
    for (int dq = 0; dq < 4; dq++) {
      bf16x8 kf = *(const bf16x8*)&Ks[krow][((dq * 2 + hl) ^ (krow & 7)) * 8];
      s = __builtin_amdgcn_mfma_f32_32x32x16_bf16(kf, qf[dq], s, 0, 0, 0);
    }
    __builtin_amdgcn_s_setprio(0);

    if (masked) {
      const int lim = q - j0 - kh * 32 - 4 * hl;   // keep if (reg&3)+8*(reg>>2) <= lim
      #pragma unroll
      for (int r = 0; r < 16; r++) {
        const int kl = (r & 3) + 8 * (r >> 2);
        if (kl > lim) s[r] = -2e30f;    // -2e30: exp2(s-m)==0 even when m=-1e30
      }
    }

    // ---- issue all 8 V^T transpose reads (latency covered by max tree) ----
    const unsigned vb =
        (unsigned)(uintptr_t)(__attribute__((address_space(3))) char*)(Vs)
        + (unsigned)voff32;
    u32x2 tv[8];
    asm volatile("ds_read_b64_tr_b16 %0, %1 offset:0"    : "=v"(tv[0]) : "v"(vb));
    asm volatile("ds_read_b64_tr_b16 %0, %1 offset:256"  : "=v"(tv[1]) : "v"(vb));
    asm volatile("ds_read_b64_tr_b16 %0, %1 offset:512"  : "=v"(tv[2]) : "v"(vb));
    asm volatile("ds_read_b64_tr_b16 %0, %1 offset:768"  : "=v"(tv[3]) : "v"(vb));
    asm volatile("ds_read_b64_tr_b16 %0, %1 offset:4096" : "=v"(tv[4]) : "v"(vb));
    asm volatile("ds_read_b64_tr_b16 %0, %1 offset:4352" : "=v"(tv[5]) : "v"(vb));
    asm volatile("ds_read_b64_tr_b16 %0, %1 offset:4608" : "=v"(tv[6]) : "v"(vb));
    asm volatile("ds_read_b64_tr_b16 %0, %1 offset:4864" : "=v"(tv[7]) : "v"(vb));

    // ---- max reduce: depth-4 tree + ONE cross-half shuffle ----
    float x0 = fmaxf(s[0], s[8]),  x1 = fmaxf(s[1], s[9]);
    float x2 = fmaxf(s[2], s[10]), x3 = fmaxf(s[3], s[11]);
    float x4 = fmaxf(s[4], s[12]), x5 = fmaxf(s[5], s[13]);
    float x6 = fmaxf(s[6], s[14]), x7 = fmaxf(s[7], s[15]);
    x0 = fmaxf(x0, x4); x1 = fmaxf(x1, x5);
    x2 = fmaxf(x2, x6); x3 = fmaxf(x3, x7);
    x0 = fmaxf(x0, x2); x1 = fmaxf(x1, x3);
    float tmax = fmaxf(x0, x1);
    tmax = fmaxf(tmax, __shfl_xor(tmax, 32));

    const bool grow = !__all(tmax <= m + 8.0f);
    float corr = 1.f;
    if (grow) {
      const float mnew = fmaxf(m, tmax);
      corr = __builtin_amdgcn_exp2f(m - mnew);
      m = mnew;
    }

    __builtin_amdgcn_s_barrier();                      // Z: all QK reads done
    if (do_stage) stageK(jn);                          // Ks dead -> overwrite

    asm volatile("s_waitcnt lgkmcnt(0)" ::: "memory"); // tr data in regs
    __builtin_amdgcn_sched_barrier(0);
    __builtin_amdgcn_s_barrier();                      // Y: all tr reads done
    if (do_stage) stageV(jn);                          // Vs dead -> overwrite

    // ---- exp2 + tree psum ----
    float ps0 = 0.f, ps1 = 0.f, ps2 = 0.f, ps3 = 0.f;
    #pragma unroll
    for (int r = 0; r < 16; r += 4) {
      float p0 = __builtin_amdgcn_exp2f(s[r]     - m);
      float p1 = __builtin_amdgcn_exp2f(s[r + 1] - m);
      float p2 = __builtin_amdgcn_exp2f(s[r + 2] - m);
      float p3 = __builtin_amdgcn_exp2f(s[r + 3] - m);
      s[r] = p0; s[r + 1] = p1; s[r + 2] = p2; s[r + 3] = p3;
      ps0 += p0; ps1 += p1; ps2 += p2; ps3 += p3;
    }
    float psum = (ps0 + ps1) + (ps2 + ps3);

    // ---- P^T B-frags: fully in-lane ----
    bf16x8 pb0, pb1;
    #pragma unroll
    for (int i2 = 0; i2 < 8; i2++) {
      pb0[i2] = (__bf16)s[i2];
      pb1[i2] = (__bf16)s[8 + i2];
    }

    // ---- O-rescale must precede PV ----
    if (grow) {
      #pragma unroll
      for (int d2 = 0; d2 < 2; d2++)
        #pragma unroll
        for (int r = 0; r < 16; r++) o_acc[d2][r] *= corr;
    }

    // ---- 4 back-to-back PV MFMAs (tv already drained) ----
    __builtin_amdgcn_s_setprio(1);
    #pragma unroll
    for (int d2 = 0; d2 < 2; d2++) {
      bf16x8 a0, a1;
      ((u32x2*)&a0)[0] = tv[d2 * 4 + 0]; ((u32x2*)&a0)[1] = tv[d2 * 4 + 1];
      ((u32x2*)&a1)[0] = tv[d2 * 4 + 2]; ((u32x2*)&a1)[1] = tv[d2 * 4 + 3];
      o_acc[d2] = __builtin_amdgcn_mfma_f32_32x32x16_bf16(a0, pb0, o_acc[d2], 0, 0, 0);
      o_acc[d2] = __builtin_amdgcn_mfma_f32_32x32x16_bf16(a1, pb1, o_acc[d2], 0, 0, 0);
    }
    __builtin_amdgcn_s_setprio(0);

    // ---- l-update (off the PV critical path) ----
    psum += __shfl_xor(psum, 32);
    l = grow ? (l * corr + psum) : (l + psum);
  };

  // prologue: stage tile it0 (X-barrier of iteration 0 drains it)
  stageK(it0 * KB);
  stageV(it0 * KB);

  const int nt = it1 - it0;
  #pragma unroll 1
  for (int tt = 0; tt < nt; tt++) {
    iter((it0 + tt) * KB, (tt == nt - 1) && diag,
         (it0 + tt + 1) * KB, tt + 1 < nt);
  }

  // ---- kh-pair merge through LDS, then epilogue by kh=0 waves ----
  __syncthreads();     // all waves done; reuse SMEM as exchange space
  float* exO  = (float*)SMEM;               // [32 rows][128 slots] f32 = 16 KB
  float* exML = (float*)(SMEM + 16384);     // [2][128] f32 = 1 KB
  const int slot = qh * 64 + lane;
  if (kh) {
    #pragma unroll
    for (int r = 0; r < 16; r++) {
      exO[r * 128 + slot]        = o_acc[0][r];
      exO[(16 + r) * 128 + slot] = o_acc[1][r];
    }
    exML[slot]       = m;
    exML[128 + slot] = l;
  }
  __syncthreads();
  if (!kh) {
    const float m1  = exML[slot];
    const float l1v = exML[128 + slot];
    const float mm = fmaxf(m, m1);
    const float c0 = __builtin_amdgcn_exp2f(m - mm);
    const float c1 = __builtin_amdgcn_exp2f(m1 - mm);
    const float lsum = l * c0 + l1v * c1;
    if (split) {
      // unnormalized f32 partial + (m,l) for attn_merge (cached workspace)
      float* prow = pO + (size_t)pidx * 4096 + (size_t)(qh * 32 + l31) * 64;
      #pragma unroll
      for (int d2 = 0; d2 < 2; d2++)
        #pragma unroll
        for (int rq = 0; rq < 4; rq++) {
          f32x4 o4;
          #pragma unroll
          for (int jj = 0; jj < 4; jj++) {
            const int r = rq * 4 + jj;
            o4[jj] = o_acc[d2][r] * c0 + exO[(d2 * 16 + r) * 128 + slot] * c1;
          }
          *(f32x4*)&prow[d2 * 32 + rq * 8 + hl * 4] = o4;
        }
      if (!hl) {
        pml[(size_t)pidx * 128 + qh * 32 + l31]      = mm;
        pml[(size_t)pidx * 128 + 64 + qh * 32 + l31] = lsum;
      }
    } else {
      const float inv = 1.f / lsum;
      __bf16* yrow = y + ((size_t)(b * S_LEN + q)) * EMB + h * DH;
      #pragma unroll
      for (int d2 = 0; d2 < 2; d2++)
        #pragma unroll
        for (int rq = 0; rq < 4; rq++) {
          bf16x4 o4;
          #pragma unroll
          for (int jj = 0; jj < 4; jj++) {
            const int r = rq * 4 + jj;
            float v = (o_acc[d2][r] * c0 + exO[(d2 * 16 + r) * 128 + slot] * c1) * inv;
            o4[jj] = (__bf16)v;
          }
          // d = d2*32 + rq*8 + hl*4 + jj
          *(bf16x4*)&yrow[d2 * 32 + rq * 8 + hl * 4] = o4;
        }
    }
  }
}

// ---------------- merge the two K-half partials of qtiles 20..31 ----------
__global__ __launch_bounds__(256)
void attn_merge(const float* __restrict__ pO, const float* __restrict__ pml,
                __bf16* __restrict__ y) {
  const int mid = blockIdx.x;            // 0..383
  const int g = mid / 12, qrel = mid % 12;
  const int qt = 20 + qrel;
  const int b = g >> 4, h = g & 15;
  const int p0 = (g * 12 + qrel) * 2, p1 = p0 + 1;
  const int row = threadIdx.x >> 2;            // 0..63
  const int d0  = (threadIdx.x & 3) * 16;      // 0,16,32,48

  const float mA = pml[(size_t)p0 * 128 + row];
  const float lA = pml[(size_t)p0 * 128 + 64 + row];
  const float mB = pml[(size_t)p1 * 128 + row];
  const float lB = pml[(size_t)p1 * 128 + 64 + row];
  const float mm = fmaxf(mA, mB);
  const float cA = __builtin_amdgcn_exp2f(mA - mm);
  const float cB = __builtin_amdgcn_exp2f(mB - mm);
  const float inv = 1.f / (lA * cA + lB * cB);

  const float* OA = pO + (size_t)p0 * 4096 + (size_t)row * 64 + d0;
  const float* OB = pO + (size_t)p1 * 4096 + (size_t)row * 64 + d0;
  __bf16* yr = y + ((size_t)(b * S_LEN + qt * 64 + row)) * EMB + h * DH + d0;
  #pragma unroll
  for (int i = 0; i < 4; i++) {
    f32x4 va = *(const f32x4*)(OA + i * 4);
    f32x4 vb = *(const f32x4*)(OB + i * 4);
    bf16x4 o;
    #pragma unroll
    for (int jj = 0; jj < 4; jj++)
      o[jj] = (__bf16)((va[jj] * cA + vb[jj] * cB) * inv);
    *(bf16x4*)(yr + i * 4) = o;
  }
}

// ---------------- Launch ----------------
extern "C" void kernel_launch(void* const* d_in, const int* in_sizes, int n_in,
                              void* d_out, int out_size, void* d_ws, size_t ws_size,
                              hipStream_t stream) {
  const float* x      = (const float*)d_in[0];  // (B, S, E)
  const float* w_attn = (const float*)d_in[1];  // (E, 3E)
  const float* w_proj = (const float*)d_in[2];  // (E, E)
  float* out = (float*)d_out;                   // (B, S, E)

  const int B = in_sizes[0] / (S_LEN * EMB);    // = 2
  const int M = B * S_LEN;                      // 4096

  // bf16 workspace layout
  __bf16* xb   = (__bf16*)d_ws;                       // M x E          (8 MB)
  __bf16* wat  = xb  + (size_t)M * EMB;               // 3E x E transp  (6 MB)
  __bf16* wpt  = wat + (size_t)QKV_LD * EMB;          // E x E transp   (2 MB)
  __bf16* qkvb = wpt + (size_t)EMB * EMB;             // M x 3E         (24 MB)
  __bf16* yb   = qkvb + (size_t)M * QKV_LD;           // M x E          (8 MB)

  // split-K partials live in CACHED ws: xb+wat (14 MB contiguous, dead after
  // gemm1).  pO = 768 x 4096 f32 = 12 MB; pml = 768 x 128 f32 = 384 KB.
  float* pO  = (float*)d_ws;
  float* pml = pO + (size_t)768 * 4096;

  // 0) fused prep: cast + both weight transposes in one launch
  {
    int n8 = (M * EMB) / 8;   // 524288 -> 2048 cast blocks
    prep_fused<<<dim3(3072), 256, 0, stream>>>(x, xb, w_attn, wat, w_proj, wpt, n8);
  }

  // 1) qkv = x @ w_attn  (bf16 out, TN=128: grid 768 = 3 blocks/CU)
  dim3 g1(QKV_LD / 128, M / TM);
  gemm_bf16_mfma<__bf16, 128><<<g1, 256, 0, stream>>>(xb, wat, qkvb, M, QKV_LD, EMB);

  // 2) y = causal_attention(qkv)  [v17: 17KB LDS, 3-barrier single-buffer]
  attn_mfma<<<dim3(1408), 256, 0, stream>>>(qkvb, yb, pO, pml);
  attn_merge<<<dim3(384), 256, 0, stream>>>(pO, pml, yb);

  // 3) out = y @ w_proj  (f32 out, TN=64: grid 512 = 2 blocks/CU)
  dim3 g3(EMB / 64, M / TM);
  gemm_bf16_mfma<float, 64><<<g3, 256, 0, stream>>>(yb, wpt, out, M, EMB, EMB);
}